// Round 2
// baseline (931.049 us; speedup 1.0000x reference)
//
#include <hip/hip_runtime.h>

// ---------------------------------------------------------------------------
// RhythmSNN forward, de-sequentialized:
//   1. split dec_w (fp32) -> K-interleaved [hi|lo] bf16 W2[32000][1024]   (ws)
//   2. state1 = gather(enc_w, raw) @ fc1          (fp32 tiled GEMM, fused gather)
//   3. scan1: membrane update over T (parallel in b,h) -> s1 (fp32 {0,1})
//   4. state2 = s1 @ fc2                          (fp32 tiled GEMM)
//   5. scan2 -> s2 duplicated along K (bf16 {0,1}) A2[4096][1024]
//   6. out = A2 @ W2^T + dec_b                    (MFMA bf16, == s2 @ (hi+lo)^T)
// Accuracy: hi/lo bf16 split reconstructs dec_w to ~2^-17 relative; membrane
// dynamics (threshold crossings) stay pure fp32.
// ---------------------------------------------------------------------------

typedef __attribute__((ext_vector_type(8))) short short8;
typedef __attribute__((ext_vector_type(4))) float f32x4;
typedef __attribute__((ext_vector_type(8))) unsigned short us8;

__device__ __forceinline__ unsigned short f2bf(float f) {
    unsigned int u = __float_as_uint(f);
    unsigned int r = (u + 0x7FFFu + ((u >> 16) & 1u)) >> 16;   // RNE
    return (unsigned short)r;
}

// ---------------- 1. split dec_w -> K-interleaved hi/lo bf16 ---------------
// flat fp32 id 4i covers (n, k..k+3); output u16 index = 2*(n*512+k) = 8i.
__global__ __launch_bounds__(256) void split_kernel(
    const float* __restrict__ w, unsigned short* __restrict__ w2, int n4)
{
    int i = blockIdx.x * 256 + threadIdx.x;
    if (i >= n4) return;
    float4 v = ((const float4*)w)[i];
    float vv[4] = {v.x, v.y, v.z, v.w};
    us8 o;
    #pragma unroll
    for (int c = 0; c < 4; ++c) {
        unsigned short hb = f2bf(vv[c]);
        float hf = __uint_as_float(((unsigned int)hb) << 16);
        o[2 * c]     = hb;
        o[2 * c + 1] = f2bf(vv[c] - hf);   // exact residual, then RNE
    }
    ((us8*)w2)[i] = o;
}

// ---------------- 2./4. fp32 tiled GEMM (64x64 tile, 4x4 microtile) --------
// C[M,N] = A[M,K] @ B[K,N];  if gidx != null, A row i = gtable[gidx[i]*K ...]
__global__ __launch_bounds__(256) void gemm_f32_kernel(
    const float* __restrict__ A, const float* __restrict__ B,
    float* __restrict__ C, int M, int N, int K,
    const int* __restrict__ gidx, const float* __restrict__ gtable)
{
    __shared__ float As[16][64];
    __shared__ float Bs[16][64];
    int tid = threadIdx.x;
    int bn0 = blockIdx.x * 64, bm0 = blockIdx.y * 64;

    int lrowA = tid >> 2;          // 0..63
    int lkA   = (tid & 3) * 4;     // 0,4,8,12
    int lkB   = tid >> 4;          // 0..15
    int lnB   = (tid & 15) * 4;
    int ty = tid >> 4, tx = tid & 15;

    const float* Abase;
    size_t aoff;
    int grow = bm0 + lrowA;
    if (gidx) { Abase = gtable; aoff = (size_t)gidx[grow] * K; }
    else      { Abase = A;      aoff = (size_t)grow * K; }

    float acc[4][4];
    #pragma unroll
    for (int i = 0; i < 4; ++i)
        #pragma unroll
        for (int j = 0; j < 4; ++j) acc[i][j] = 0.f;

    for (int k0 = 0; k0 < K; k0 += 16) {
        float4 av = *(const float4*)(Abase + aoff + k0 + lkA);
        As[lkA + 0][lrowA] = av.x;
        As[lkA + 1][lrowA] = av.y;
        As[lkA + 2][lrowA] = av.z;
        As[lkA + 3][lrowA] = av.w;
        float4 bv = *(const float4*)(B + (size_t)(k0 + lkB) * N + bn0 + lnB);
        *(float4*)&Bs[lkB][lnB] = bv;
        __syncthreads();
        #pragma unroll
        for (int kk = 0; kk < 16; ++kk) {
            float4 aq = *(float4*)&As[kk][ty * 4];
            float4 bq = *(float4*)&Bs[kk][tx * 4];
            float aa[4] = {aq.x, aq.y, aq.z, aq.w};
            float bb[4] = {bq.x, bq.y, bq.z, bq.w};
            #pragma unroll
            for (int i = 0; i < 4; ++i)
                #pragma unroll
                for (int j = 0; j < 4; ++j) acc[i][j] += aa[i] * bb[j];
        }
        __syncthreads();
    }
    #pragma unroll
    for (int i = 0; i < 4; ++i) {
        float4 v = {acc[i][0], acc[i][1], acc[i][2], acc[i][3]};
        *(float4*)(C + (size_t)(bm0 + ty * 4 + i) * N + bn0 + tx * 4) = v;
    }
}

// ---------------- 3./5. membrane scan (parallel over b,h; T unrolled) ------
// DUP=0: write spike fp32 [T*B][512].  DUP=1: write spike bf16 duplicated
// along K: u32 = bf|bf<<16 at row stride 512 u32 (= [T*B][1024] u16).
template <int DUP>
__global__ __launch_bounds__(64) void scan_kernel(
    const float* __restrict__ state, const float* __restrict__ mask,
    float* __restrict__ outF, unsigned int* __restrict__ outU)
{
    int tid = blockIdx.x * 64 + threadIdx.x;   // < 32*512
    int b = tid >> 9, h = tid & 511;
    const float* mrow = mask + (size_t)h * 3136;   // mask row, first 128 used
    float mem = 0.f;
    #pragma unroll
    for (int t = 0; t < 128; ++t) {
        size_t ridx = (size_t)(t * 32 + b) * 512 + h;
        float st = state[ridx];
        float m  = mrow[t];
        // reset uses OLD mem: new_mem = (mem>thr) ? state : mem*decay + state
        float nm = (mem > 0.6f) ? st : mem * 0.6f + st;
        mem = (m == 0.0f) ? mem : nm;
        float spf = (mem > 0.6f) ? m : 0.0f;        // heaviside(mem-thr) * m
        if (DUP) {
            unsigned int bb = f2bf(spf);
            outU[ridx] = bb * 0x10001u;             // duplicate along K
        } else {
            outF[ridx] = spf;
        }
    }
}

// ---------------- 6. decode GEMM: bf16 MFMA, 128x128 tile -----------------
// C[4096, 32000] = A[4096,1024] @ W[32000,1024]^T + bias
__global__ __launch_bounds__(256) void gemm3_kernel(
    const unsigned short* __restrict__ A,
    const unsigned short* __restrict__ W,
    const float* __restrict__ bias, float* __restrict__ C)
{
    constexpr int K = 1024, NTOK = 32000;
    __shared__ unsigned short sA[128 * 64];
    __shared__ unsigned short sB[128 * 64];

    int tid  = threadIdx.x;
    int lane = tid & 63;
    int wid  = __builtin_amdgcn_readfirstlane(tid >> 6);

    // XCD-aware swizzle: 8000 blocks, 8000 % 8 == 0 -> bijective.
    // mt fast within an XCD's contiguous swz range -> one B panel reused
    // by ~32 co-resident blocks while A-tiles stream through L2.
    int bid = blockIdx.x;
    int swz = (bid & 7) * 1000 + (bid >> 3);
    int mt = swz & 31;        // 32 M-tiles
    int nt = swz >> 5;        // 250 N-tiles
    int m0 = mt * 128, n0 = nt * 128;

    int wm = wid >> 1, wn = wid & 1;   // wave's 64x64 quadrant

    f32x4 acc[4][4];
    #pragma unroll
    for (int i = 0; i < 4; ++i)
        #pragma unroll
        for (int j = 0; j < 4; ++j) acc[i][j] = (f32x4){0.f, 0.f, 0.f, 0.f};

    for (int it = 0; it < 16; ++it) {
        int k0 = it * 64;

        // Stage A/B tiles [128 rows x 64 k] bf16 = 16KB each.
        // LDS is linear (global_load_lds dest = wave-uniform base + lane*16);
        // swizzle applied on the SOURCE: LDS[row][c] = G[row][c ^ (row&7)]
        // (chunk = 16B), undone identically on the read side (rule #21).
        #pragma unroll
        for (int i = 0; i < 4; ++i) {
            int q   = i * 256 + wid * 64 + lane;   // chunk id 0..1023
            int row = q >> 3;
            int cb  = q & 7;
            int scb = cb ^ (row & 7);
            const unsigned short* ga = A + (size_t)(m0 + row) * K + k0 + scb * 8;
            const unsigned short* gb = W + (size_t)(n0 + row) * K + k0 + scb * 8;
            unsigned short* la = sA + (size_t)(i * 256 + wid * 64) * 8;
            unsigned short* lb = sB + (size_t)(i * 256 + wid * 64) * 8;
            __builtin_amdgcn_global_load_lds(
                (const __attribute__((address_space(1))) unsigned int*)ga,
                (__attribute__((address_space(3))) unsigned int*)la, 16, 0, 0);
            __builtin_amdgcn_global_load_lds(
                (const __attribute__((address_space(1))) unsigned int*)gb,
                (__attribute__((address_space(3))) unsigned int*)lb, 16, 0, 0);
        }
        __syncthreads();   // drains vmcnt before barrier (compiler-enforced)

        #pragma unroll
        for (int ks = 0; ks < 2; ++ks) {
            short8 fa[4], fb[4];
            int kb = ks * 64 + ((lane >> 4) << 4);   // byte offset in 128B row
            #pragma unroll
            for (int f = 0; f < 4; ++f) {
                int rowA = wm * 64 + f * 16 + (lane & 15);
                int adA  = rowA * 128 + (kb ^ ((rowA & 7) << 4));
                fa[f] = *(const short8*)((const char*)sA + adA);
                int rowB = wn * 64 + f * 16 + (lane & 15);
                int adB  = rowB * 128 + (kb ^ ((rowB & 7) << 4));
                fb[f] = *(const short8*)((const char*)sB + adB);
            }
            #pragma unroll
            for (int mf = 0; mf < 4; ++mf)
                #pragma unroll
                for (int nf = 0; nf < 4; ++nf)
                    acc[mf][nf] = __builtin_amdgcn_mfma_f32_16x16x32_bf16(
                        fa[mf], fb[nf], acc[mf][nf], 0, 0, 0);
        }
        __syncthreads();
    }

    // epilogue: C/D layout col = lane&15, row = (lane>>4)*4 + reg  [m89]
    int lr = lane >> 4, lc = lane & 15;
    #pragma unroll
    for (int mf = 0; mf < 4; ++mf) {
        #pragma unroll
        for (int nf = 0; nf < 4; ++nf) {
            int gr = m0 + wm * 64 + mf * 16 + lr * 4;
            int gc = n0 + wn * 64 + nf * 16 + lc;
            float bv = bias[gc];
            f32x4 v = acc[mf][nf];
            #pragma unroll
            for (int j = 0; j < 4; ++j)
                C[(size_t)(gr + j) * NTOK + gc] = v[j] + bv;
        }
    }
}

// ---------------------------------------------------------------------------
extern "C" void kernel_launch(void* const* d_in, const int* in_sizes, int n_in,
                              void* d_out, int out_size, void* d_ws, size_t ws_size,
                              hipStream_t stream)
{
    const int*   raw   = (const int*)  d_in[0];
    const float* enc_w = (const float*)d_in[1];
    const float* fc1   = (const float*)d_in[2];
    const float* fc2   = (const float*)d_in[3];
    const float* dec_w = (const float*)d_in[4];
    const float* dec_b = (const float*)d_in[5];
    const float* mask1 = (const float*)d_in[6];
    const float* mask2 = (const float*)d_in[7];
    float* out = (float*)d_out;

    const int T = 128, B = 32, H1 = 512, H2 = 512, NINP = 256, NTOK = 32000;
    const int M = T * B;   // 4096

    // ws layout (total 81.6 MB):
    //   [0,8MB)    st   : state1, then state2 (fp32 [4096][512])
    //   [8,16MB)   spF  : s1 fp32 [4096][512]; later reused as A2 (s2 dup bf16
    //              [4096][1024]) -- s1 is dead after gemm2.
    //   [16MB,+65.5MB) W2: K-interleaved hi/lo bf16 [32000][1024]
    char* ws = (char*)d_ws;
    float*          st  = (float*)ws;
    float*          spF = (float*)(ws + (size_t)(8u << 20));
    unsigned int*   a2u = (unsigned int*)(ws + (size_t)(8u << 20));
    unsigned short* A2  = (unsigned short*)(ws + (size_t)(8u << 20));
    unsigned short* W2  = (unsigned short*)(ws + (size_t)(16u << 20));

    // 1. split dec_w -> W2 (re-run every call; ws is re-poisoned)
    int n4 = NTOK * H2 / 4;
    split_kernel<<<(n4 + 255) / 256, 256, 0, stream>>>(dec_w, W2, n4);

    // 2. state1 = gather(enc_w, raw) @ fc1
    gemm_f32_kernel<<<dim3(H1 / 64, M / 64), 256, 0, stream>>>(
        nullptr, fc1, st, M, H1, NINP, raw, enc_w);

    // 3. scan1 -> s1 (fp32)
    scan_kernel<0><<<(B * H1) / 64, 64, 0, stream>>>(st, mask1, spF, nullptr);

    // 4. state2 = s1 @ fc2
    gemm_f32_kernel<<<dim3(H2 / 64, M / 64), 256, 0, stream>>>(
        spF, fc2, st, M, H2, H1, nullptr, nullptr);

    // 5. scan2 -> s2 duplicated bf16 (overwrites dead s1 region)
    scan_kernel<1><<<(B * H2) / 64, 64, 0, stream>>>(st, mask2, nullptr, a2u);

    // 6. out = A2 @ W2^T + dec_b
    gemm3_kernel<<<(M / 128) * (NTOK / 128), 256, 0, stream>>>(A2, W2, dec_b, out);

    (void)in_sizes; (void)n_in; (void)out_size; (void)ws_size;
}